// Round 1
// baseline (37.855 us; speedup 1.0000x reference)
//
#include <hip/hip_runtime.h>
#include <cstdint>
#include <cmath>

#define EPS_F 1e-8f

constexpr int B = 8, H = 8, CELLS = 8192, W = 256;
constexpr int TC = 32;          // cells per block in scores kernel
constexpr int W4 = W / 4;       // 64 float4 per W-row

// ---------------------------------------------------------------------------
// Kernel 1: scores[b,h,c] = dots/(kn*mem_norm + eps) * beta
// grid = (CELLS/TC, B), block = 256
// ---------------------------------------------------------------------------
__global__ __launch_bounds__(256, 2) void ca_scores_kernel(
    const float* __restrict__ memory,   // [B, CELLS, W]
    const float* __restrict__ keys,     // [B, H, W]
    const float* __restrict__ betas,    // [B, H]
    const float* __restrict__ mask,     // [B, H, W]
    float* __restrict__ out)            // [B, H, CELLS] (scores, pre-softmax)
{
    __shared__ float4 s_mem[TC * W4];   // 32 KB, XOR-swizzled per row
    __shared__ float4 s_kq[H * W4];     // 8 KB : keys * m^2
    __shared__ float4 s_m2[H * W4];     // 8 KB : m^2
    __shared__ float  s_red[4 * H];
    __shared__ float  s_kn[H];

    const int t  = threadIdx.x;
    const int b  = blockIdx.y;
    const int c0 = blockIdx.x * TC;

    // ---- prep: kq, m2, keys_norm for this b (tiny, L2-resident) ----
    const float* kb = keys + (size_t)b * H * W;
    const float* mb = mask + (size_t)b * H * W;
    float km2[H];
#pragma unroll
    for (int i = 0; i < H; ++i) {       // element (h=i, w=t)
        float k  = kb[i * W + t];
        float m  = mb[i * W + t];       // MASK_MIN = 0 -> mask unchanged
        float m2 = m * m;
        ((float*)s_kq)[i * W + t] = k * m2;
        ((float*)s_m2)[i * W + t] = m2;
        float km = k * m;
        km2[i] = km * km;
    }

    // ---- stage memory tile (coalesced global read, swizzled LDS write) ----
    const float4* mg = (const float4*)(memory + ((size_t)b * CELLS + c0) * W);
#pragma unroll
    for (int i = 0; i < 8; ++i) {
        int s  = t + i * 256;           // f4 slot 0..2047
        int c  = s >> 6;                // /W4
        int w4 = s & 63;
        s_mem[c * W4 + (w4 ^ (c & 7))] = mg[s];
    }

    // ---- block-reduce keys_norm^2 per head ----
    const int lane = t & 63, wv = t >> 6;
#pragma unroll
    for (int i = 0; i < H; ++i) {
        float v = km2[i];
#pragma unroll
        for (int s = 32; s; s >>= 1) v += __shfl_xor(v, s, 64);
        if (lane == 0) s_red[wv * H + i] = v;
    }
    __syncthreads();
    if (t < H) {
        float v = (s_red[t] + s_red[H + t]) + (s_red[2 * H + t] + s_red[3 * H + t]);
        s_kn[t] = sqrtf(v);
    }
    __syncthreads();

    // ---- main loop: thread t = h*32 + cl ----
    const int h  = t >> 5;
    const int cl = t & 31;
    const float4* pm = s_mem + cl * W4;
    const float4* pk = s_kq + h * W4;
    const float4* pq = s_m2 + h * W4;
    const int sw = cl & 7;

    float4 d4 = make_float4(0.f, 0.f, 0.f, 0.f);
    float4 n4 = make_float4(0.f, 0.f, 0.f, 0.f);
#pragma unroll 4
    for (int w4 = 0; w4 < W4; ++w4) {
        float4 mv = pm[w4 ^ sw];        // swizzled, conflict-free
        float4 kv = pk[w4];             // 32-lane broadcast
        float4 qv = pq[w4];             // 32-lane broadcast
        d4.x = fmaf(mv.x, kv.x, d4.x);
        d4.y = fmaf(mv.y, kv.y, d4.y);
        d4.z = fmaf(mv.z, kv.z, d4.z);
        d4.w = fmaf(mv.w, kv.w, d4.w);
        n4.x = fmaf(mv.x * mv.x, qv.x, n4.x);
        n4.y = fmaf(mv.y * mv.y, qv.y, n4.y);
        n4.z = fmaf(mv.z * mv.z, qv.z, n4.z);
        n4.w = fmaf(mv.w * mv.w, qv.w, n4.w);
    }
    float dots = (d4.x + d4.y) + (d4.z + d4.w);
    float nrm  = (n4.x + n4.y) + (n4.z + n4.w);

    float kn    = s_kn[h];
    float beta  = betas[b * H + h];
    float score = dots * beta / (kn * sqrtf(nrm) + EPS_F);

    out[((size_t)(b * H + h)) * CELLS + c0 + cl] = score;
}

// ---------------------------------------------------------------------------
// Kernel 2: in-place softmax over C=8192 per (b,h) row.
// grid = B*H = 64, block = 256; each thread owns 32 values in registers.
// ---------------------------------------------------------------------------
__global__ __launch_bounds__(256, 2) void ca_softmax_kernel(float* __restrict__ data)
{
    __shared__ float s_red[4];
    __shared__ float s_sum[4];

    const int row = blockIdx.x;
    float4* p = (float4*)(data + (size_t)row * CELLS);   // 2048 f4
    const int t = threadIdx.x;
    const int lane = t & 63, wv = t >> 6;

    float4 v[8];
    float mx = -INFINITY;
#pragma unroll
    for (int i = 0; i < 8; ++i) {
        v[i] = p[t + i * 256];
        mx = fmaxf(mx, fmaxf(fmaxf(v[i].x, v[i].y), fmaxf(v[i].z, v[i].w)));
    }
#pragma unroll
    for (int s = 32; s; s >>= 1) mx = fmaxf(mx, __shfl_xor(mx, s, 64));
    if (lane == 0) s_red[wv] = mx;
    __syncthreads();
    mx = fmaxf(fmaxf(s_red[0], s_red[1]), fmaxf(s_red[2], s_red[3]));

    float sum = 0.f;
#pragma unroll
    for (int i = 0; i < 8; ++i) {
        v[i].x = expf(v[i].x - mx);
        v[i].y = expf(v[i].y - mx);
        v[i].z = expf(v[i].z - mx);
        v[i].w = expf(v[i].w - mx);
        sum += (v[i].x + v[i].y) + (v[i].z + v[i].w);
    }
#pragma unroll
    for (int s = 32; s; s >>= 1) sum += __shfl_xor(sum, s, 64);
    if (lane == 0) s_sum[wv] = sum;
    __syncthreads();
    sum = (s_sum[0] + s_sum[1]) + (s_sum[2] + s_sum[3]);

    float inv = 1.0f / sum;
#pragma unroll
    for (int i = 0; i < 8; ++i) {
        v[i].x *= inv; v[i].y *= inv; v[i].z *= inv; v[i].w *= inv;
        p[t + i * 256] = v[i];
    }
}

// ---------------------------------------------------------------------------
extern "C" void kernel_launch(void* const* d_in, const int* in_sizes, int n_in,
                              void* d_out, int out_size, void* d_ws, size_t ws_size,
                              hipStream_t stream) {
    (void)in_sizes; (void)n_in; (void)out_size; (void)d_ws; (void)ws_size;
    const float* memory = (const float*)d_in[0];
    const float* keys   = (const float*)d_in[1];
    const float* betas  = (const float*)d_in[2];
    const float* mask   = (const float*)d_in[3];
    float* out = (float*)d_out;

    dim3 g1(CELLS / TC, B);
    ca_scores_kernel<<<g1, 256, 0, stream>>>(memory, keys, betas, mask, out);
    ca_softmax_kernel<<<B * H, 256, 0, stream>>>(out);
}